// Round 1
// baseline (3594.399 us; speedup 1.0000x reference)
//
#include <hip/hip_runtime.h>
#include <hip/hip_bf16.h>
#include <stdint.h>

// Chebyshev KAN: two layers of  out[b,o] = sum_{i,d} T_d(xhat[b,i]) * C[i,o,d]
// = GEMM with virtual A (Chebyshev-expanded, built on the fly in LDS) and
// repacked bf16 B. MFMA 16x16x32 bf16, 128x128 block tile, 4 waves of 64x64.

constexpr int BATCH   = 16384;
constexpr int IN_DIM  = 1024;
constexpr int HID_DIM = 2048;
constexpr int OUT_DIM = 1024;
#define DP1 9  // degree+1

using bf16_t = __hip_bfloat16;

typedef __attribute__((ext_vector_type(4))) float f32x4;
typedef __attribute__((ext_vector_type(8))) short s16x8;

static __device__ __forceinline__ unsigned int f2bf_u(float f) {
  union { __hip_bfloat16 h; unsigned short u; } cv;
  cv.h = __float2bfloat16(f);
  return (unsigned int)cv.u;
}

// ---------------- min/max over batch, per column (two stage) ----------------
template <typename T>
__global__ void kan_minmax_partial(const T* __restrict__ x, int rows, int cols,
                                   float* __restrict__ mnp, float* __restrict__ mxp) {
  // grid: (cols/64, P); block 256 = 64 cols x 4 row-groups
  const int c  = blockIdx.x * 64 + (threadIdx.x & 63);
  const int rg = threadIdx.x >> 6;  // 0..3
  const int P  = gridDim.y;
  const int chunk = rows / P;
  const int r0 = blockIdx.y * chunk;
  float mn = 1e30f, mx = -1e30f;
  for (int r = r0 + rg; r < r0 + chunk; r += 4) {
    float v = (float)x[(size_t)r * cols + c];
    mn = fminf(mn, v); mx = fmaxf(mx, v);
  }
  __shared__ float smn[256], smx[256];
  smn[threadIdx.x] = mn; smx[threadIdx.x] = mx;
  __syncthreads();
  if (rg == 0) {
    int t = threadIdx.x;
    mn = fminf(fminf(smn[t], smn[t + 64]), fminf(smn[t + 128], smn[t + 192]));
    mx = fmaxf(fmaxf(smx[t], smx[t + 64]), fmaxf(smx[t + 128], smx[t + 192]));
    mnp[(size_t)blockIdx.y * cols + c] = mn;
    mxp[(size_t)blockIdx.y * cols + c] = mx;
  }
}

__global__ void kan_minmax_finalize(const float* __restrict__ mnp, const float* __restrict__ mxp,
                                    int cols, int P, float* __restrict__ s, float* __restrict__ t) {
  int c = blockIdx.x * blockDim.x + threadIdx.x;
  if (c >= cols) return;
  float mn = 1e30f, mx = -1e30f;
  for (int p = 0; p < P; ++p) {
    mn = fminf(mn, mnp[(size_t)p * cols + c]);
    mx = fmaxf(mx, mxp[(size_t)p * cols + c]);
  }
  float inv = 2.0f / (mx - mn);
  s[c] = inv;                  // xhat = inv*x + t
  t[c] = -mn * inv - 1.0f;
}

// ------------- repack coeffs [I,O,9] fp32 -> Bp[o][k] bf16, k=ib*288+d*32+ii -------------
__global__ void kan_repack(const float* __restrict__ coeffs, int I, int O,
                           bf16_t* __restrict__ Bp) {
  // grid (I/32, O/128), block 256
  const int ib = blockIdx.x;
  const int o0 = blockIdx.y * 128;
  const size_t K = (size_t)I * DP1;
  for (int idx = threadIdx.x; idx < 128 * 288; idx += 256) {
    int ol = idx / 288;
    int kk = idx - ol * 288;
    int d  = kk >> 5;
    int ii = kk & 31;
    int i  = ib * 32 + ii;
    float v = coeffs[((size_t)i * O + (o0 + ol)) * DP1 + d];
    Bp[(size_t)(o0 + ol) * K + (size_t)ib * 288 + kk] = __float2bfloat16(v);
  }
}

// ---------------- fused Chebyshev-expand + bf16 MFMA GEMM ----------------
// grid: (BATCH/128, N/128). block 256 = 4 waves in 2x2, each wave 64x64 out.
template <typename AT, typename OT>
__launch_bounds__(256, 2)
__global__ void kan_cheby_gemm(const AT* __restrict__ X, const bf16_t* __restrict__ Bp,
                               const float* __restrict__ sc, const float* __restrict__ tc,
                               OT* __restrict__ out, int I, int N) {
  constexpr int LDK = 104;  // LDS row stride in bf16 elems (96 data + 8 pad -> 2-way free)
  __shared__ __align__(16) short Als[128 * LDK];
  __shared__ __align__(16) short Bls[128 * LDK];

  const int m0   = blockIdx.x * 128;
  const int n0   = blockIdx.y * 128;
  const int tid  = threadIdx.x;
  const int lane = tid & 63;
  const int wave = tid >> 6;
  const int wm   = (wave >> 1) * 64;
  const int wn   = (wave & 1) * 64;
  const int quad = lane >> 4;
  const int l16  = lane & 15;

  // staging ownership: 2 threads per row; hf selects 16-feature / 48-k half
  const int ma = tid >> 1;
  const int hf = tid & 1;

  const size_t K = (size_t)I * DP1;
  const int NIB = I / 32;

  f32x4 acc[4][4] = {};

  for (int ib = 0; ib < NIB; ++ib) {
    // ---- load 16 x values (row m0+ma, features ib*32+hf*16 ..+15), normalize
    const int fbase = ib * 32 + hf * 16;
    float xv[16];
    {
      const AT* xp = X + (size_t)(m0 + ma) * I + fbase;
      if constexpr (sizeof(AT) == 4) {
        const float4* p4 = reinterpret_cast<const float4*>(xp);
#pragma unroll
        for (int v = 0; v < 4; ++v) {
          float4 f = p4[v];
          xv[4 * v + 0] = f.x; xv[4 * v + 1] = f.y;
          xv[4 * v + 2] = f.z; xv[4 * v + 3] = f.w;
        }
      } else {
        const uint4* p4 = reinterpret_cast<const uint4*>(xp);
#pragma unroll
        for (int v = 0; v < 2; ++v) {
          uint4 u = p4[v];
          unsigned int wv[4] = {u.x, u.y, u.z, u.w};
#pragma unroll
          for (int q = 0; q < 4; ++q) {
            xv[8 * v + 2 * q + 0] = __uint_as_float(wv[q] << 16);
            xv[8 * v + 2 * q + 1] = __uint_as_float(wv[q] & 0xffff0000u);
          }
        }
      }
      const float4* sp = reinterpret_cast<const float4*>(sc + fbase);
      const float4* tp = reinterpret_cast<const float4*>(tc + fbase);
#pragma unroll
      for (int v = 0; v < 4; ++v) {
        float4 sv = sp[v], tv = tp[v];
        xv[4 * v + 0] = fmaf(xv[4 * v + 0], sv.x, tv.x);
        xv[4 * v + 1] = fmaf(xv[4 * v + 1], sv.y, tv.y);
        xv[4 * v + 2] = fmaf(xv[4 * v + 2], sv.z, tv.z);
        xv[4 * v + 3] = fmaf(xv[4 * v + 3], sv.w, tv.w);
      }
    }

    float Tm1[16], Tm2[16];
#pragma unroll
    for (int j = 0; j < 16; ++j) { Tm1[j] = 0.f; Tm2[j] = 0.f; }

#pragma unroll
    for (int ph = 0; ph < 3; ++ph) {
      // prefetch B slab chunk into regs (row n0+nb=ma, 48 k's at hf*96 bytes)
      uint4 breg[6];
      {
        const char* src = reinterpret_cast<const char*>(Bp) +
            ((size_t)(n0 + ma) * K + (size_t)ib * 288 + ph * 96) * 2 + hf * 96;
#pragma unroll
        for (int cc = 0; cc < 6; ++cc)
          breg[cc] = *reinterpret_cast<const uint4*>(src + cc * 16);
      }

      __syncthreads();  // previous stage's LDS reads complete

      // write B slab
      {
        char* dst = reinterpret_cast<char*>(Bls) + ma * (LDK * 2) + hf * 96;
#pragma unroll
        for (int cc = 0; cc < 6; ++cc)
          *reinterpret_cast<uint4*>(dst + cc * 16) = breg[cc];
      }

      // compute 3 Chebyshev rows, pack bf16, write A slab
#pragma unroll
      for (int dl = 0; dl < 3; ++dl) {
        const int dd = ph * 3 + dl;
        float tv[16];
        if (dd == 0) {
#pragma unroll
          for (int j = 0; j < 16; ++j) tv[j] = 1.0f;
        } else if (dd == 1) {
#pragma unroll
          for (int j = 0; j < 16; ++j) tv[j] = xv[j];
        } else {
#pragma unroll
          for (int j = 0; j < 16; ++j) tv[j] = fmaf(2.0f * xv[j], Tm1[j], -Tm2[j]);
        }
#pragma unroll
        for (int j = 0; j < 16; ++j) { Tm2[j] = Tm1[j]; Tm1[j] = tv[j]; }

        unsigned int pk[8];
#pragma unroll
        for (int q = 0; q < 8; ++q)
          pk[q] = f2bf_u(tv[2 * q]) | (f2bf_u(tv[2 * q + 1]) << 16);
        char* adst = reinterpret_cast<char*>(Als) + ma * (LDK * 2) + dl * 64 + hf * 32;
        *reinterpret_cast<uint4*>(adst +  0) = make_uint4(pk[0], pk[1], pk[2], pk[3]);
        *reinterpret_cast<uint4*>(adst + 16) = make_uint4(pk[4], pk[5], pk[6], pk[7]);
      }

      __syncthreads();  // LDS writes visible

      // 3 k-steps of MFMA over the 96-wide stage
#pragma unroll
      for (int ks = 0; ks < 3; ++ks) {
        const int kb = ks * 64 + quad * 16;  // byte offset within LDS row
        s16x8 fa[4], fb[4];
#pragma unroll
        for (int mt = 0; mt < 4; ++mt) {
          const char* ap = reinterpret_cast<const char*>(Als) +
                           (wm + mt * 16 + l16) * (LDK * 2) + kb;
          fa[mt] = *reinterpret_cast<const s16x8*>(ap);
        }
#pragma unroll
        for (int nt = 0; nt < 4; ++nt) {
          const char* bp = reinterpret_cast<const char*>(Bls) +
                           (wn + nt * 16 + l16) * (LDK * 2) + kb;
          fb[nt] = *reinterpret_cast<const s16x8*>(bp);
        }
#pragma unroll
        for (int mt = 0; mt < 4; ++mt)
#pragma unroll
          for (int nt = 0; nt < 4; ++nt)
            acc[mt][nt] = __builtin_amdgcn_mfma_f32_16x16x32_bf16(
                fa[mt], fb[nt], acc[mt][nt], 0, 0, 0);
      }
    }
  }

  // epilogue: C/D layout col=lane&15 (n), row=quad*4+reg (m)  [m89-verified]
#pragma unroll
  for (int mt = 0; mt < 4; ++mt) {
#pragma unroll
    for (int nt = 0; nt < 4; ++nt) {
      const int n = n0 + wn + nt * 16 + l16;
#pragma unroll
      for (int r = 0; r < 4; ++r) {
        const int m = m0 + wm + mt * 16 + quad * 4 + r;
        float v = acc[mt][nt][r];
        if constexpr (sizeof(OT) == 4)
          out[(size_t)m * N + n] = v;
        else
          out[(size_t)m * N + n] = __float2bfloat16(v);
      }
    }
  }
}

// ---------------- launcher ----------------
extern "C" void kernel_launch(void* const* d_in, const int* in_sizes, int n_in,
                              void* d_out, int out_size, void* d_ws, size_t ws_size,
                              hipStream_t stream) {
  const float* x  = (const float*)d_in[0];
  const float* c1 = (const float*)d_in[1];
  const float* c2 = (const float*)d_in[2];
  float* out = (float*)d_out;

  char* ws = (char*)d_ws;
  size_t off = 0;
  auto take = [&](size_t n) -> char* {
    char* p = ws + off;
    off += (n + 255) & ~(size_t)255;
    return p;
  };
  bf16_t* Bp1 = (bf16_t*)take((size_t)HID_DIM * IN_DIM  * DP1 * 2);  // 37.75 MB
  bf16_t* Bp2 = (bf16_t*)take((size_t)OUT_DIM * HID_DIM * DP1 * 2);  // 37.75 MB
  bf16_t* h   = (bf16_t*)take((size_t)BATCH * HID_DIM * 2);          // 67 MB
  float* s1  = (float*)take(IN_DIM  * 4);
  float* t1  = (float*)take(IN_DIM  * 4);
  float* s2  = (float*)take(HID_DIM * 4);
  float* t2  = (float*)take(HID_DIM * 4);
  float* mnp = (float*)take((size_t)16 * HID_DIM * 4);
  float* mxp = (float*)take((size_t)16 * HID_DIM * 4);

  // layer 1
  kan_minmax_partial<float><<<dim3(IN_DIM / 64, 16), 256, 0, stream>>>(x, BATCH, IN_DIM, mnp, mxp);
  kan_minmax_finalize<<<dim3(IN_DIM / 256), 256, 0, stream>>>(mnp, mxp, IN_DIM, 16, s1, t1);
  kan_repack<<<dim3(IN_DIM / 32, HID_DIM / 128), 256, 0, stream>>>(c1, IN_DIM, HID_DIM, Bp1);
  kan_repack<<<dim3(HID_DIM / 32, OUT_DIM / 128), 256, 0, stream>>>(c2, HID_DIM, OUT_DIM, Bp2);
  kan_cheby_gemm<float, bf16_t><<<dim3(BATCH / 128, HID_DIM / 128), 256, 0, stream>>>(
      x, Bp1, s1, t1, h, IN_DIM, HID_DIM);

  // layer 2
  kan_minmax_partial<bf16_t><<<dim3(HID_DIM / 64, 16), 256, 0, stream>>>(h, BATCH, HID_DIM, mnp, mxp);
  kan_minmax_finalize<<<dim3(HID_DIM / 256), 256, 0, stream>>>(mnp, mxp, HID_DIM, 16, s2, t2);
  kan_cheby_gemm<bf16_t, float><<<dim3(BATCH / 128, OUT_DIM / 128), 256, 0, stream>>>(
      h, Bp2, s2, t2, out, HID_DIM, OUT_DIM);
}

// Round 3
// 2215.743 us; speedup vs baseline: 1.6222x; 1.6222x over previous
//
#include <hip/hip_runtime.h>
#include <hip/hip_bf16.h>
#include <stdint.h>

// Chebyshev KAN: two layers of  out[b,o] = sum_{i,d} T_d(xhat[b,i]) * C[i,o,d]
// GEMM with virtual A (Chebyshev built on the fly) and repacked bf16 B.
// Round 3: fix kan_repack slab coverage (1024 chunks, not 512 — R2 wrote only
// cols 0..127 of each 256-col tile, leaving half of B as poison).
// Structure: fragment-order LDS, B via global_load_lds double-buffered,
// block tile 128x256, wave tile 64x128, stage = 32 k (1 degree).

constexpr int BATCH   = 16384;
constexpr int IN_DIM  = 1024;
constexpr int HID_DIM = 2048;
constexpr int OUT_DIM = 1024;
#define DP1 9  // degree+1

using bf16_t = __hip_bfloat16;

typedef __attribute__((ext_vector_type(4))) float f32x4;
typedef __attribute__((ext_vector_type(8))) short s16x8;

static __device__ __forceinline__ unsigned int f2bf_u(float f) {
  union { __hip_bfloat16 h; unsigned short u; } cv;
  cv.h = __float2bfloat16(f);
  return (unsigned int)cv.u;
}

// ---------------- min/max over batch, per column (two stage) ----------------
template <typename T>
__global__ void kan_minmax_partial(const T* __restrict__ x, int rows, int cols,
                                   float* __restrict__ mnp, float* __restrict__ mxp) {
  const int c  = blockIdx.x * 64 + (threadIdx.x & 63);
  const int rg = threadIdx.x >> 6;
  const int P  = gridDim.y;
  const int chunk = rows / P;
  const int r0 = blockIdx.y * chunk;
  float mn = 1e30f, mx = -1e30f;
  for (int r = r0 + rg; r < r0 + chunk; r += 4) {
    float v = (float)x[(size_t)r * cols + c];
    mn = fminf(mn, v); mx = fmaxf(mx, v);
  }
  __shared__ float smn[256], smx[256];
  smn[threadIdx.x] = mn; smx[threadIdx.x] = mx;
  __syncthreads();
  if (rg == 0) {
    int t = threadIdx.x;
    mn = fminf(fminf(smn[t], smn[t + 64]), fminf(smn[t + 128], smn[t + 192]));
    mx = fmaxf(fmaxf(smx[t], smx[t + 64]), fmaxf(smx[t + 128], smx[t + 192]));
    mnp[(size_t)blockIdx.y * cols + c] = mn;
    mxp[(size_t)blockIdx.y * cols + c] = mx;
  }
}

__global__ void kan_minmax_finalize(const float* __restrict__ mnp, const float* __restrict__ mxp,
                                    int cols, int P, float* __restrict__ s, float* __restrict__ t) {
  int c = blockIdx.x * blockDim.x + threadIdx.x;
  if (c >= cols) return;
  float mn = 1e30f, mx = -1e30f;
  for (int p = 0; p < P; ++p) {
    mn = fminf(mn, mnp[(size_t)p * cols + c]);
    mx = fmaxf(mx, mxp[(size_t)p * cols + c]);
  }
  float inv = 2.0f / (mx - mn);
  s[c] = inv;
  t[c] = -mn * inv - 1.0f;
}

// ---- repack coeffs [I,O,9] fp32 -> Bp in B-fragment order, bf16 ----
// slab = (ntile*NIB + ib)*9 + d   (8192 bf16 per slab = 256 cols x 32 k
//                                  = 1024 chunks of 16 B)
// within slab: chunk c = ng*64 + quad*16 + l16, elem j:
//   o = ntile*256 + ng*16 + l16 ; i = ib*32 + quad*8 + j
__global__ void kan_repack(const float* __restrict__ coeffs, int I, int O,
                           bf16_t* __restrict__ Bp) {
  const int NIB = I / 32;
  const int slab = blockIdx.x;
  const int d  = slab % 9;
  const int t2 = slab / 9;
  const int ib = t2 % NIB;
  const int ntile = t2 / NIB;
  for (int c = threadIdx.x; c < 1024; c += 256) {   // R3 fix: full 1024 chunks
    const int l16  = c & 15;
    const int quad = (c >> 4) & 3;
    const int ng   = c >> 6;                        // 0..15 (256 cols)
    const int o = ntile * 256 + ng * 16 + l16;
    const int ibase = ib * 32 + quad * 8;
    unsigned int pk[4];
#pragma unroll
    for (int q = 0; q < 4; ++q) {
      float v0 = coeffs[((size_t)(ibase + 2 * q + 0) * O + o) * DP1 + d];
      float v1 = coeffs[((size_t)(ibase + 2 * q + 1) * O + o) * DP1 + d];
      pk[q] = f2bf_u(v0) | (f2bf_u(v1) << 16);
    }
    *reinterpret_cast<uint4*>(reinterpret_cast<char*>(Bp) +
        ((size_t)slab * 8192 + (size_t)c * 8) * 2) = make_uint4(pk[0], pk[1], pk[2], pk[3]);
  }
}

// ---------------- fused Chebyshev-expand + bf16 MFMA GEMM ----------------
// block tile 128(m) x 256(n); 4 waves 2x2; wave tile 64x128 (acc 4x8).
// A: 8 KB single buffer, fragment order. B: 2 x 16 KB double buffer via
// global_load_lds (contiguous copy of pre-fragmented slab).
template <typename AT, typename OT>
__launch_bounds__(256, 2)
__global__ void kan_cheby_gemm(const AT* __restrict__ X, const bf16_t* __restrict__ Bp,
                               const float* __restrict__ sc, const float* __restrict__ tc,
                               OT* __restrict__ out, int I, int N) {
  __shared__ __align__(16) short Als[4096];        //  8 KB: 128 rows x 32 k
  __shared__ __align__(16) short Bls[2][8192];     // 2x16 KB: 256 cols x 32 k

  const int m0   = blockIdx.x * 128;
  const int n0   = blockIdx.y * 256;
  const int tid  = threadIdx.x;
  const int lane = tid & 63;
  const int wave = tid >> 6;
  const int wr   = wave >> 1;          // m half
  const int wc   = wave & 1;           // n half
  const int wm4  = wr * 4;             // 16-row-group base (m)
  const int wn16 = wc * 8;             // 16-col-group base (n)
  const int quad = lane >> 4;
  const int l16  = lane & 15;

  // producer: thread owns row ma, features hf*16..+15 of the current 32-block
  const int ma = tid & 127;
  const int hf = tid >> 7;

  const int NIB = I / 32;
  const int nstage = NIB * 9;
  const size_t slab_base = (size_t)blockIdx.y * NIB * 9 * 8192;  // bf16 elems

  auto dma_b = [&](int ss) {
    const char* g = reinterpret_cast<const char*>(Bp + slab_base + (size_t)ss * 8192) +
                    wave * 4096 + lane * 16;
    char* l = reinterpret_cast<char*>(&Bls[ss & 1][0]) + wave * 4096;
#pragma unroll
    for (int t = 0; t < 4; ++t)
      __builtin_amdgcn_global_load_lds(
          (const __attribute__((address_space(1))) void*)(g + t * 1024),
          (__attribute__((address_space(3))) void*)(l + t * 1024), 16, 0, 0);
  };

  f32x4 acc[4][8] = {};
  float xv[16], Tm1[16], Tm2[16];
#pragma unroll
  for (int j = 0; j < 16; ++j) { xv[j] = 0.f; Tm1[j] = 0.f; Tm2[j] = 0.f; }

  dma_b(0);

  int ib = 0, d = 0;
  for (int s = 0; s < nstage; ++s) {
    __syncthreads();  // barrier A: MFMA(s-1) done -> A buffer free; B(s) DMA drained

    if (d == 0) {
      // load 16 x values for row m0+ma, features ib*32+hf*16.., normalize
      const int fbase = ib * 32 + hf * 16;
      const AT* xp = X + (size_t)(m0 + ma) * I + fbase;
      if constexpr (sizeof(AT) == 4) {
        const float4* p4 = reinterpret_cast<const float4*>(xp);
#pragma unroll
        for (int v = 0; v < 4; ++v) {
          float4 f = p4[v];
          xv[4 * v + 0] = f.x; xv[4 * v + 1] = f.y;
          xv[4 * v + 2] = f.z; xv[4 * v + 3] = f.w;
        }
      } else {
        const uint4* p4 = reinterpret_cast<const uint4*>(xp);
#pragma unroll
        for (int v = 0; v < 2; ++v) {
          uint4 u = p4[v];
          unsigned int wv[4] = {u.x, u.y, u.z, u.w};
#pragma unroll
          for (int q = 0; q < 4; ++q) {
            xv[8 * v + 2 * q + 0] = __uint_as_float(wv[q] << 16);
            xv[8 * v + 2 * q + 1] = __uint_as_float(wv[q] & 0xffff0000u);
          }
        }
      }
      const float4* sp = reinterpret_cast<const float4*>(sc + fbase);
      const float4* tp = reinterpret_cast<const float4*>(tc + fbase);
#pragma unroll
      for (int v = 0; v < 4; ++v) {
        float4 sv = sp[v], tv4 = tp[v];
        xv[4 * v + 0] = fmaf(xv[4 * v + 0], sv.x, tv4.x);
        xv[4 * v + 1] = fmaf(xv[4 * v + 1], sv.y, tv4.y);
        xv[4 * v + 2] = fmaf(xv[4 * v + 2], sv.z, tv4.z);
        xv[4 * v + 3] = fmaf(xv[4 * v + 3], sv.w, tv4.w);
      }
    }

    // produce degree-d row: tv[16], update recurrence, pack, 2 chunk writes
    {
      float tv[16];
      if (d == 0) {
#pragma unroll
        for (int j = 0; j < 16; ++j) tv[j] = 1.0f;
      } else if (d == 1) {
#pragma unroll
        for (int j = 0; j < 16; ++j) tv[j] = xv[j];
      } else {
#pragma unroll
        for (int j = 0; j < 16; ++j) tv[j] = fmaf(2.0f * xv[j], Tm1[j], -Tm2[j]);
      }
#pragma unroll
      for (int j = 0; j < 16; ++j) { Tm2[j] = Tm1[j]; Tm1[j] = tv[j]; }

      unsigned int pk[8];
#pragma unroll
      for (int q = 0; q < 8; ++q)
        pk[q] = f2bf_u(tv[2 * q]) | (f2bf_u(tv[2 * q + 1]) << 16);
      // chunk = (ma>>4)*64 + (2*hf+c)*16 + (ma&15); byte addr = chunk*16
      char* b = reinterpret_cast<char*>(Als) +
                (ma >> 4) * 1024 + hf * 512 + (ma & 15) * 16;
      *reinterpret_cast<uint4*>(b)       = make_uint4(pk[0], pk[1], pk[2], pk[3]);
      *reinterpret_cast<uint4*>(b + 256) = make_uint4(pk[4], pk[5], pk[6], pk[7]);
    }

    __syncthreads();  // barrier B: A visible

    if (s + 1 < nstage) dma_b(s + 1);  // window = the MFMA section below

    // MFMA: one 32-k step; lane-contiguous fragment reads
    {
      const char* Ab = reinterpret_cast<const char*>(Als) + lane * 16;
      const char* Bb = reinterpret_cast<const char*>(&Bls[s & 1][0]) + lane * 16;
      s16x8 fa[4], fb[8];
#pragma unroll
      for (int mt = 0; mt < 4; ++mt)
        fa[mt] = *reinterpret_cast<const s16x8*>(Ab + (wm4 + mt) * 1024);
#pragma unroll
      for (int nt = 0; nt < 8; ++nt)
        fb[nt] = *reinterpret_cast<const s16x8*>(Bb + (wn16 + nt) * 1024);
#pragma unroll
      for (int mt = 0; mt < 4; ++mt)
#pragma unroll
        for (int nt = 0; nt < 8; ++nt)
          acc[mt][nt] = __builtin_amdgcn_mfma_f32_16x16x32_bf16(
              fa[mt], fb[nt], acc[mt][nt], 0, 0, 0);
    }

    if (++d == DP1) { d = 0; ++ib; }
  }

  // epilogue: C/D layout col = lane&15 (n), row = quad*4 + reg (m)
#pragma unroll
  for (int mt = 0; mt < 4; ++mt) {
#pragma unroll
    for (int nt = 0; nt < 8; ++nt) {
      const int n = n0 + wc * 128 + nt * 16 + l16;
#pragma unroll
      for (int r = 0; r < 4; ++r) {
        const int m = m0 + wr * 64 + mt * 16 + quad * 4 + r;
        float v = acc[mt][nt][r];
        if constexpr (sizeof(OT) == 4)
          out[(size_t)m * N + n] = v;
        else
          out[(size_t)m * N + n] = __float2bfloat16(v);
      }
    }
  }
}

// ---------------- launcher ----------------
extern "C" void kernel_launch(void* const* d_in, const int* in_sizes, int n_in,
                              void* d_out, int out_size, void* d_ws, size_t ws_size,
                              hipStream_t stream) {
  const float* x  = (const float*)d_in[0];
  const float* c1 = (const float*)d_in[1];
  const float* c2 = (const float*)d_in[2];
  float* out = (float*)d_out;

  char* ws = (char*)d_ws;
  size_t off = 0;
  auto take = [&](size_t n) -> char* {
    char* p = ws + off;
    off += (n + 255) & ~(size_t)255;
    return p;
  };
  bf16_t* Bp1 = (bf16_t*)take((size_t)HID_DIM * IN_DIM  * DP1 * 2);  // 37.75 MB
  bf16_t* Bp2 = (bf16_t*)take((size_t)OUT_DIM * HID_DIM * DP1 * 2);  // 37.75 MB
  bf16_t* h   = (bf16_t*)take((size_t)BATCH * HID_DIM * 2);          // 67 MB
  float* s1  = (float*)take(IN_DIM  * 4);
  float* t1  = (float*)take(IN_DIM  * 4);
  float* s2  = (float*)take(HID_DIM * 4);
  float* t2  = (float*)take(HID_DIM * 4);
  float* mnp = (float*)take((size_t)16 * HID_DIM * 4);
  float* mxp = (float*)take((size_t)16 * HID_DIM * 4);

  // layer 1
  kan_minmax_partial<float><<<dim3(IN_DIM / 64, 16), 256, 0, stream>>>(x, BATCH, IN_DIM, mnp, mxp);
  kan_minmax_finalize<<<dim3(IN_DIM / 256), 256, 0, stream>>>(mnp, mxp, IN_DIM, 16, s1, t1);
  kan_repack<<<dim3((HID_DIM / 256) * (IN_DIM / 32) * 9), 256, 0, stream>>>(c1, IN_DIM, HID_DIM, Bp1);
  kan_repack<<<dim3((OUT_DIM / 256) * (HID_DIM / 32) * 9), 256, 0, stream>>>(c2, HID_DIM, OUT_DIM, Bp2);
  kan_cheby_gemm<float, bf16_t><<<dim3(BATCH / 128, HID_DIM / 256), 256, 0, stream>>>(
      x, Bp1, s1, t1, h, IN_DIM, HID_DIM);

  // layer 2
  kan_minmax_partial<bf16_t><<<dim3(HID_DIM / 64, 16), 256, 0, stream>>>(h, BATCH, HID_DIM, mnp, mxp);
  kan_minmax_finalize<<<dim3(HID_DIM / 256), 256, 0, stream>>>(mnp, mxp, HID_DIM, 16, s2, t2);
  kan_cheby_gemm<bf16_t, float><<<dim3(BATCH / 128, OUT_DIM / 256), 256, 0, stream>>>(
      h, Bp2, s2, t2, out, HID_DIM, OUT_DIM);
}

// Round 4
// 1867.614 us; speedup vs baseline: 1.9246x; 1.1864x over previous
//
#include <hip/hip_runtime.h>
#include <hip/hip_bf16.h>
#include <stdint.h>

// Chebyshev KAN: two layers of  out[b,o] = sum_{i,d} T_d(xhat[b,i]) * C[i,o,d]
// GEMM with virtual A (Chebyshev built on the fly) and repacked bf16 B.
// Round 4: single barrier per stage (A double-buffered like B), x prefetched
// one ib ahead, packed bf16 conversion, line-once repack.
// Block tile 128x256, wave tile 64x128, stage = 32 k (1 degree).

constexpr int BATCH   = 16384;
constexpr int IN_DIM  = 1024;
constexpr int HID_DIM = 2048;
constexpr int OUT_DIM = 1024;
#define DP1 9  // degree+1

using bf16_t = __hip_bfloat16;

typedef __attribute__((ext_vector_type(4))) float f32x4;
typedef __attribute__((ext_vector_type(8))) short s16x8;
typedef __attribute__((ext_vector_type(16))) float f32x16;
typedef __attribute__((ext_vector_type(16))) __bf16 bf16x16;

static __device__ __forceinline__ unsigned int f2bf_u(float f) {
  union { __hip_bfloat16 h; unsigned short u; } cv;
  cv.h = __float2bfloat16(f);
  return (unsigned int)cv.u;
}

// ---------------- min/max over batch, per column (two stage) ----------------
template <typename T>
__global__ void kan_minmax_partial(const T* __restrict__ x, int rows, int cols,
                                   float* __restrict__ mnp, float* __restrict__ mxp) {
  const int c  = blockIdx.x * 64 + (threadIdx.x & 63);
  const int rg = threadIdx.x >> 6;
  const int P  = gridDim.y;
  const int chunk = rows / P;
  const int r0 = blockIdx.y * chunk;
  float mn = 1e30f, mx = -1e30f;
  for (int r = r0 + rg; r < r0 + chunk; r += 4) {
    float v = (float)x[(size_t)r * cols + c];
    mn = fminf(mn, v); mx = fmaxf(mx, v);
  }
  __shared__ float smn[256], smx[256];
  smn[threadIdx.x] = mn; smx[threadIdx.x] = mx;
  __syncthreads();
  if (rg == 0) {
    int t = threadIdx.x;
    mn = fminf(fminf(smn[t], smn[t + 64]), fminf(smn[t + 128], smn[t + 192]));
    mx = fmaxf(fmaxf(smx[t], smx[t + 64]), fmaxf(smx[t + 128], smx[t + 192]));
    mnp[(size_t)blockIdx.y * cols + c] = mn;
    mxp[(size_t)blockIdx.y * cols + c] = mx;
  }
}

__global__ void kan_minmax_finalize(const float* __restrict__ mnp, const float* __restrict__ mxp,
                                    int cols, int P, float* __restrict__ s, float* __restrict__ t) {
  int c = blockIdx.x * blockDim.x + threadIdx.x;
  if (c >= cols) return;
  float mn = 1e30f, mx = -1e30f;
  for (int p = 0; p < P; ++p) {
    mn = fminf(mn, mnp[(size_t)p * cols + c]);
    mx = fmaxf(mx, mxp[(size_t)p * cols + c]);
  }
  float inv = 2.0f / (mx - mn);
  s[c] = inv;
  t[c] = -mn * inv - 1.0f;
}

// ---- repack coeffs [I,O,9] fp32 -> Bp in B-fragment order, bf16 ----
// R4: one block owns ALL 9 d-slabs of an (ntile, ib) pair, so the stride-9
// gather reads each cache line once (d-neighbors hit L1) instead of 9x HBM.
// slab = (ntile*NIB + ib)*9 + d ; within slab chunk c = ng*64 + quad*16 + l16:
//   o = ntile*256 + ng*16 + l16 ; i = ib*32 + quad*8 + j
__global__ void kan_repack(const float* __restrict__ coeffs, int I, int O,
                           bf16_t* __restrict__ Bp) {
  const int NIB = I / 32;
  const int ib = blockIdx.x % NIB;
  const int ntile = blockIdx.x / NIB;
  const size_t slab0 = (size_t)(ntile * NIB + ib) * 9 * 8192;  // bf16 elems
  for (int c = threadIdx.x; c < 1024; c += 256) {
    const int l16  = c & 15;
    const int quad = (c >> 4) & 3;
    const int ng   = c >> 6;
    const int o = ntile * 256 + ng * 16 + l16;
    const int ibase = ib * 32 + quad * 8;
    float v[8][9];
#pragma unroll
    for (int q = 0; q < 8; ++q) {
      const float* rp = coeffs + ((size_t)(ibase + q) * O + o) * DP1;
#pragma unroll
      for (int d = 0; d < 9; ++d) v[q][d] = rp[d];
    }
#pragma unroll
    for (int d = 0; d < 9; ++d) {
      unsigned int pk[4];
#pragma unroll
      for (int q = 0; q < 4; ++q)
        pk[q] = f2bf_u(v[2 * q][d]) | (f2bf_u(v[2 * q + 1][d]) << 16);
      *reinterpret_cast<uint4*>(reinterpret_cast<char*>(Bp) +
          (slab0 + (size_t)d * 8192 + (size_t)c * 8) * 2) =
          make_uint4(pk[0], pk[1], pk[2], pk[3]);
    }
  }
}

// ---------------- fused Chebyshev-expand + bf16 MFMA GEMM ----------------
// block tile 128(m) x 256(n); 4 waves 2x2; wave tile 64x128 (acc 4x8).
// A: 2x8 KB double buffer (fragment order). B: 2x16 KB double buffer via
// global_load_lds. ONE barrier per stage: stage s MFMAs buffers [s&1] while
// producing A[(s+1)&1] and DMA-ing B[(s+1)&1]; all hazards >=1 barrier apart.
template <typename AT, typename OT>
__launch_bounds__(256, 2)
__global__ void kan_cheby_gemm(const AT* __restrict__ X, const bf16_t* __restrict__ Bp,
                               const float* __restrict__ sc, const float* __restrict__ tc,
                               OT* __restrict__ out, int I, int N) {
  __shared__ __align__(16) short Als[2][4096];     // 2x 8 KB: 128 rows x 32 k
  __shared__ __align__(16) short Bls[2][8192];     // 2x16 KB: 256 cols x 32 k

  const int m0   = blockIdx.x * 128;
  const int tid  = threadIdx.x;
  const int lane = tid & 63;
  const int wave = tid >> 6;
  const int wr   = wave >> 1;          // m half
  const int wc   = wave & 1;           // n half
  const int wm4  = wr * 4;             // 16-row-group base (m)
  const int wn16 = wc * 8;             // 16-col-group base (n)
  const int quad = lane >> 4;
  const int l16  = lane & 15;

  // producer: thread owns row ma, features hf*16..+15 of the current 32-block
  const int ma = tid & 127;
  const int hf = tid >> 7;

  const int NIB = I / 32;
  const int nstage = NIB * 9;
  const size_t slab_base = (size_t)blockIdx.y * NIB * 9 * 8192;  // bf16 elems

  auto dma_b = [&](int ss) {
    const char* g = reinterpret_cast<const char*>(Bp + slab_base + (size_t)ss * 8192) +
                    wave * 4096 + lane * 16;
    char* l = reinterpret_cast<char*>(&Bls[ss & 1][0]) + wave * 4096;
#pragma unroll
    for (int t = 0; t < 4; ++t)
      __builtin_amdgcn_global_load_lds(
          (const __attribute__((address_space(1))) void*)(g + t * 1024),
          (__attribute__((address_space(3))) void*)(l + t * 1024), 16, 0, 0);
  };

  uint4 rq[4];  // raw x bits (prefetched one ib ahead)
  auto load_raw = [&](int ibx) {
    const char* xp = reinterpret_cast<const char*>(
        X + (size_t)(m0 + ma) * I + ibx * 32 + hf * 16);
    if constexpr (sizeof(AT) == 4) {
      rq[0] = *reinterpret_cast<const uint4*>(xp +  0);
      rq[1] = *reinterpret_cast<const uint4*>(xp + 16);
      rq[2] = *reinterpret_cast<const uint4*>(xp + 32);
      rq[3] = *reinterpret_cast<const uint4*>(xp + 48);
    } else {
      rq[0] = *reinterpret_cast<const uint4*>(xp +  0);
      rq[1] = *reinterpret_cast<const uint4*>(xp + 16);
    }
  };

  f32x16 xv, Tm1, Tm2;
#pragma unroll
  for (int j = 0; j < 16; ++j) { xv[j] = 0.f; Tm1[j] = 0.f; Tm2[j] = 0.f; }

  auto unpack_norm = [&](int ibx) {
    const int fbase = ibx * 32 + hf * 16;
    float rv[16];
    const unsigned int* w = reinterpret_cast<const unsigned int*>(rq);
    if constexpr (sizeof(AT) == 4) {
#pragma unroll
      for (int j = 0; j < 16; ++j) rv[j] = __uint_as_float(w[j]);
    } else {
#pragma unroll
      for (int q = 0; q < 8; ++q) {
        rv[2 * q + 0] = __uint_as_float(w[q] << 16);
        rv[2 * q + 1] = __uint_as_float(w[q] & 0xffff0000u);
      }
    }
    const float4* sp = reinterpret_cast<const float4*>(sc + fbase);
    const float4* tp = reinterpret_cast<const float4*>(tc + fbase);
#pragma unroll
    for (int v = 0; v < 4; ++v) {
      float4 s4 = sp[v], t4 = tp[v];
      xv[4 * v + 0] = fmaf(rv[4 * v + 0], s4.x, t4.x);
      xv[4 * v + 1] = fmaf(rv[4 * v + 1], s4.y, t4.y);
      xv[4 * v + 2] = fmaf(rv[4 * v + 2], s4.z, t4.z);
      xv[4 * v + 3] = fmaf(rv[4 * v + 3], s4.w, t4.w);
    }
  };

  // write producer row tv into A buffer `buf` (fragment order, 2 chunks)
  auto write_a = [&](int buf, const f32x16& tv) {
    union { bf16x16 v; uint4 q[2]; } u;
    u.v = __builtin_convertvector(tv, bf16x16);  // v_cvt_pk_bf16_f32 on gfx950
    char* b = reinterpret_cast<char*>(&Als[buf][0]) +
              (ma >> 4) * 1024 + hf * 512 + (ma & 15) * 16;
    *reinterpret_cast<uint4*>(b)       = u.q[0];
    *reinterpret_cast<uint4*>(b + 256) = u.q[1];
  };

  f32x4 acc[4][8] = {};

  // ---- prologue: stage 0 is (ib=0, d=0) = all-ones row; prefetch x(ib0)
  load_raw(0);
  dma_b(0);
  {
    f32x16 ones;
#pragma unroll
    for (int j = 0; j < 16; ++j) ones[j] = 1.0f;
    write_a(0, ones);
    Tm1 = ones;
  }
  __syncthreads();

  int dn = 1, ibn = 0;  // degree/ib of the NEXT stage to produce (t = s+1)
  for (int s = 0; s < nstage; ++s) {
    // ---- produce stage s+1 into buffers [(s+1)&1]
    if (s + 1 < nstage) {
      dma_b(s + 1);
      f32x16 tv;
      if (dn == 0) {
#pragma unroll
        for (int j = 0; j < 16; ++j) tv[j] = 1.0f;
      } else if (dn == 1) {
        unpack_norm(ibn);                       // normalize prefetched raw
        if (ibn + 1 < NIB) load_raw(ibn + 1);   // prefetch next ib (8 stages early)
        tv = xv;
      } else {
        tv = 2.0f * xv * Tm1 - Tm2;
      }
      Tm2 = Tm1; Tm1 = tv;
      write_a((s + 1) & 1, tv);
      if (++dn == DP1) { dn = 0; ++ibn; }
    }

    // ---- consume stage s: fragment reads + 32 MFMA
    {
      const char* Ab = reinterpret_cast<const char*>(&Als[s & 1][0]) + lane * 16;
      const char* Bb = reinterpret_cast<const char*>(&Bls[s & 1][0]) + lane * 16;
      s16x8 fa[4], fb[8];
#pragma unroll
      for (int mt = 0; mt < 4; ++mt)
        fa[mt] = *reinterpret_cast<const s16x8*>(Ab + (wm4 + mt) * 1024);
#pragma unroll
      for (int nt = 0; nt < 8; ++nt)
        fb[nt] = *reinterpret_cast<const s16x8*>(Bb + (wn16 + nt) * 1024);
#pragma unroll
      for (int mt = 0; mt < 4; ++mt)
#pragma unroll
        for (int nt = 0; nt < 8; ++nt)
          acc[mt][nt] = __builtin_amdgcn_mfma_f32_16x16x32_bf16(
              fa[mt], fb[nt], acc[mt][nt], 0, 0, 0);
    }

    __syncthreads();  // single barrier: publishes A/B[(s+1)&1], frees [s&1]
  }

  // epilogue: C/D layout col = lane&15 (n), row = quad*4 + reg (m)
  const int n0 = blockIdx.y * 256;
#pragma unroll
  for (int mt = 0; mt < 4; ++mt) {
#pragma unroll
    for (int nt = 0; nt < 8; ++nt) {
      const int n = n0 + wc * 128 + nt * 16 + l16;
#pragma unroll
      for (int r = 0; r < 4; ++r) {
        const int m = m0 + wr * 64 + mt * 16 + quad * 4 + r;
        float v = acc[mt][nt][r];
        if constexpr (sizeof(OT) == 4)
          out[(size_t)m * N + n] = v;
        else
          out[(size_t)m * N + n] = __float2bfloat16(v);
      }
    }
  }
}

// ---------------- launcher ----------------
extern "C" void kernel_launch(void* const* d_in, const int* in_sizes, int n_in,
                              void* d_out, int out_size, void* d_ws, size_t ws_size,
                              hipStream_t stream) {
  const float* x  = (const float*)d_in[0];
  const float* c1 = (const float*)d_in[1];
  const float* c2 = (const float*)d_in[2];
  float* out = (float*)d_out;

  char* ws = (char*)d_ws;
  size_t off = 0;
  auto take = [&](size_t n) -> char* {
    char* p = ws + off;
    off += (n + 255) & ~(size_t)255;
    return p;
  };
  bf16_t* Bp1 = (bf16_t*)take((size_t)HID_DIM * IN_DIM  * DP1 * 2);  // 37.75 MB
  bf16_t* Bp2 = (bf16_t*)take((size_t)OUT_DIM * HID_DIM * DP1 * 2);  // 37.75 MB
  bf16_t* h   = (bf16_t*)take((size_t)BATCH * HID_DIM * 2);          // 67 MB
  float* s1  = (float*)take(IN_DIM  * 4);
  float* t1  = (float*)take(IN_DIM  * 4);
  float* s2  = (float*)take(HID_DIM * 4);
  float* t2  = (float*)take(HID_DIM * 4);
  float* mnp = (float*)take((size_t)16 * HID_DIM * 4);
  float* mxp = (float*)take((size_t)16 * HID_DIM * 4);

  // layer 1
  kan_minmax_partial<float><<<dim3(IN_DIM / 64, 16), 256, 0, stream>>>(x, BATCH, IN_DIM, mnp, mxp);
  kan_minmax_finalize<<<dim3(IN_DIM / 256), 256, 0, stream>>>(mnp, mxp, IN_DIM, 16, s1, t1);
  kan_repack<<<dim3((HID_DIM / 256) * (IN_DIM / 32)), 256, 0, stream>>>(c1, IN_DIM, HID_DIM, Bp1);
  kan_repack<<<dim3((OUT_DIM / 256) * (HID_DIM / 32)), 256, 0, stream>>>(c2, HID_DIM, OUT_DIM, Bp2);
  kan_cheby_gemm<float, bf16_t><<<dim3(BATCH / 128, HID_DIM / 256), 256, 0, stream>>>(
      x, Bp1, s1, t1, h, IN_DIM, HID_DIM);

  // layer 2
  kan_minmax_partial<bf16_t><<<dim3(HID_DIM / 64, 16), 256, 0, stream>>>(h, BATCH, HID_DIM, mnp, mxp);
  kan_minmax_finalize<<<dim3(HID_DIM / 256), 256, 0, stream>>>(mnp, mxp, HID_DIM, 16, s2, t2);
  kan_cheby_gemm<bf16_t, float><<<dim3(BATCH / 128, OUT_DIM / 256), 256, 0, stream>>>(
      h, Bp2, s2, t2, out, HID_DIM, OUT_DIM);
}